// Round 7
// baseline (275.309 us; speedup 1.0000x reference)
//
#include <hip/hip_runtime.h>
#include <math.h>

#define NB 64      // batch N
#define LL 128     // n_in capsules
#define DD 768     // feature dim
#define ID 64      // in_dim
#define OD 64      // out_dim
#define NO 32      // n_out
#define EPSF 1e-8f

typedef unsigned short ushort_t;
typedef __attribute__((ext_vector_type(8))) short bf16x8;
typedef __attribute__((ext_vector_type(4))) float f32x4;

// ws layout (floats):
//  V     : NB*LL*NO*OD = 16777216 fp32  [n][l][o*64+j]
//    Cpart: 6*524288 = 3145728 (aliases V front; consumed pre-k1)
//    apart: 6*8192   = 49152   (aliases V;       consumed pre-k1)
//  Ah/Al : 2 x 524288 ushorts = 524288 floats   dual-bf16 mu_in [l][n][i]
//  f_a   : 8192
//  S1p   : 16*NB*NO*OD = 2097152   chunk partials [c][n][o][j]
//  S2p   : 2097152
//  dnp   : 16*NB*NO = 32768 ; aUp : 32768
//  mu_s  : 131072 ; i2v_s : 131072 ; cterm : 2048

__device__ __forceinline__ float gelu_exact(float v) {
  return 0.5f * v * (1.0f + erff(v * 0.70710678118654752440f));
}
__device__ __forceinline__ float sigmoidf_(float z) {
  return 1.0f / (1.0f + __expf(-z));
}
__device__ __forceinline__ unsigned short f2bf(float f) {  // RNE
  unsigned u = __float_as_uint(f);
  unsigned r = (u + 0x7FFFu + ((u >> 16) & 1u)) >> 16;
  return (unsigned short)r;
}
__device__ __forceinline__ float bf2f(unsigned short s) {
  return __uint_as_float(((unsigned)s) << 16);
}

// ---------------- k0a: split-K partial GEMM for the projections (unchanged).
__global__ __launch_bounds__(256) void k0a_proj(
    const float* __restrict__ x, const float* __restrict__ Wscore,
    const float* __restrict__ Wcap,
    float* __restrict__ Cpart, float* __restrict__ apart)
{
  const int l  = blockIdx.x & 127;
  const int kc = blockIdx.x >> 7;
  const int t = threadIdx.x;
  const int tn = t >> 4;
  const int ti = t & 15;
  __shared__ float Xs[64][68];
  __shared__ float Ws[64][68];
  __shared__ float Ss[64];
  float C[4][4] = {{0.f}};
  float asum[4] = {0.f, 0.f, 0.f, 0.f};

  for (int kt = 0; kt < 2; ++kt) {
    const int kbase = kc * 128 + kt * 64;
#pragma unroll
    for (int r = 0; r < 4; ++r) {
      const int flat = r * 1024 + t * 4;
      const int p = flat >> 6, qq = flat & 63;
      *(float4*)&Xs[p][qq] = *(const float4*)&x[(p * LL + l) * DD + kbase + qq];
      *(float4*)&Ws[p][qq] = *(const float4*)&Wcap[(l * DD + kbase + p) * ID + qq];
    }
    if (t < 16)
      *(float4*)&Ss[4 * t] = *(const float4*)&Wscore[l * DD + kbase + 4 * t];
    __syncthreads();
#pragma unroll 8
    for (int k = 0; k < 64; ++k) {
      float av[4];
      av[0] = Xs[4 * tn + 0][k];
      av[1] = Xs[4 * tn + 1][k];
      av[2] = Xs[4 * tn + 2][k];
      av[3] = Xs[4 * tn + 3][k];
      const float4 b = *(const float4*)&Ws[k][4 * ti];
      const float sk = Ss[k];
#pragma unroll
      for (int a = 0; a < 4; ++a) {
        C[a][0] = fmaf(av[a], b.x, C[a][0]);
        C[a][1] = fmaf(av[a], b.y, C[a][1]);
        C[a][2] = fmaf(av[a], b.z, C[a][2]);
        C[a][3] = fmaf(av[a], b.w, C[a][3]);
        asum[a] = fmaf(av[a], sk, asum[a]);
      }
    }
    __syncthreads();
  }
#pragma unroll
  for (int a = 0; a < 4; ++a)
    *(float4*)&Cpart[kc * 524288 + (l * 64 + 4 * tn + a) * 64 + 4 * ti] =
        make_float4(C[a][0], C[a][1], C[a][2], C[a][3]);
  if (ti == 0) {   // asum complete per K-slice in every ti-thread; no reduce
#pragma unroll
    for (int a = 0; a < 4; ++a)
      apart[kc * 8192 + l * 64 + 4 * tn + a] = asum[a];
  }
}

// ---------------- k0b: reduce partials + bias + gelu -> dual-bf16 mu_in
__global__ __launch_bounds__(256) void k0b_reduce(
    const float* __restrict__ Cpart, const float* __restrict__ Bcap,
    ushort_t* __restrict__ Ah, ushort_t* __restrict__ Al)
{
  const int e = (blockIdx.x * 256 + threadIdx.x) * 4;
  float4 s = *(const float4*)&Cpart[e];
#pragma unroll
  for (int kc = 1; kc < 6; ++kc) {
    const float4 p = *(const float4*)&Cpart[kc * 524288 + e];
    s.x += p.x; s.y += p.y; s.z += p.z; s.w += p.w;
  }
  const int l = e >> 12;
  const int col = e & 63;
  const float4 bc = *(const float4*)&Bcap[l * 64 + col];
  float m[4] = {gelu_exact(s.x + bc.x), gelu_exact(s.y + bc.y),
                gelu_exact(s.z + bc.z), gelu_exact(s.w + bc.w)};
  ushort4 h, lo;
  h.x = f2bf(m[0]); lo.x = f2bf(m[0] - bf2f(h.x));
  h.y = f2bf(m[1]); lo.y = f2bf(m[1] - bf2f(h.y));
  h.z = f2bf(m[2]); lo.z = f2bf(m[2] - bf2f(h.z));
  h.w = f2bf(m[3]); lo.w = f2bf(m[3] - bf2f(h.w));
  *(ushort4*)&Ah[e] = h;
  *(ushort4*)&Al[e] = lo;
}

// ---------------- k0c: reduce asum partials + Bscore -> f_a (sigmoid)
__global__ __launch_bounds__(256) void k0c_fa(
    const float* __restrict__ apart, const float* __restrict__ Bscore,
    float* __restrict__ f_a)
{
  const int e = blockIdx.x * 256 + threadIdx.x;
  float s = 0.f;
#pragma unroll
  for (int kc = 0; kc < 6; ++kc) s += apart[kc * 8192 + e];
  const int l = e >> 6;
  f_a[e] = sigmoidf_(s + Bscore[l]);
}

// ---------------- k1 v3: V = mu_in @ Wvote + Bvote, split-bf16 MFMA (3-term),
// ZERO LDS: B fragments loaded directly from fp32 Wvote at fragment positions
// (each dword-load instruction: 4 fully-used 64B segments), converted to hi/lo
// bf16 in registers. One wave per (l,o). grid 1024 x 256.
__global__ __launch_bounds__(256, 2) void k1_votes(
    const ushort_t* __restrict__ Ah, const ushort_t* __restrict__ Al,
    const float* __restrict__ Wvote, const float* __restrict__ Bvote,
    float* __restrict__ V)
{
  const int t = threadIdx.x;
  const int w = t >> 6;
  const int lane = t & 63;
  const int pair = blockIdx.x * 4 + w;    // l*NO + o
  const int l = pair >> 5;
  const int mr = lane & 15, q = lane >> 4;

  // A fragments (hi/lo) from global (L2-hot: 8 KB per l, shared by 32 o's)
  bf16x8 afh[2][4], afl[2][4];
#pragma unroll
  for (int ks = 0; ks < 2; ++ks)
#pragma unroll
    for (int mt = 0; mt < 4; ++mt) {
      const int off = l * 4096 + (16 * mt + mr) * 64 + ks * 32 + q * 8;
      afh[ks][mt] = *(const bf16x8*)&Ah[off];
      afl[ks][mt] = *(const bf16x8*)&Al[off];
    }

  // B raw fp32 at fragment positions: B[n=16nt+mr][k=ks*32+q*8+d]
  const float* Wt = Wvote + (size_t)pair * 4096;   // [i=k][j=n]
  float braw[2][4][8];
#pragma unroll
  for (int ks = 0; ks < 2; ++ks)
#pragma unroll
    for (int nt = 0; nt < 4; ++nt)
#pragma unroll
      for (int d = 0; d < 8; ++d)
        braw[ks][nt][d] = Wt[(ks * 32 + q * 8 + d) * 64 + 16 * nt + mr];

  f32x4 acc[4][4];
#pragma unroll
  for (int mt = 0; mt < 4; ++mt)
#pragma unroll
    for (int nt = 0; nt < 4; ++nt) {
      f32x4 z = {0.f, 0.f, 0.f, 0.f};
      acc[mt][nt] = z;
    }

#pragma unroll
  for (int ks = 0; ks < 2; ++ks)
#pragma unroll
    for (int nt = 0; nt < 4; ++nt) {
      union { ushort_t u[8]; bf16x8 v; } bh, bl;
#pragma unroll
      for (int d = 0; d < 8; ++d) {
        const float x = braw[ks][nt][d];
        const unsigned short hi = f2bf(x);
        bh.u[d] = hi;
        bl.u[d] = f2bf(x - bf2f(hi));
      }
#pragma unroll
      for (int mt = 0; mt < 4; ++mt) {
        acc[mt][nt] = __builtin_amdgcn_mfma_f32_16x16x32_bf16(
            afh[ks][mt], bh.v, acc[mt][nt], 0, 0, 0);
        acc[mt][nt] = __builtin_amdgcn_mfma_f32_16x16x32_bf16(
            afh[ks][mt], bl.v, acc[mt][nt], 0, 0, 0);
        acc[mt][nt] = __builtin_amdgcn_mfma_f32_16x16x32_bf16(
            afl[ks][mt], bh.v, acc[mt][nt], 0, 0, 0);
      }
    }

  float bv[4];
#pragma unroll
  for (int nt = 0; nt < 4; ++nt) bv[nt] = Bvote[pair * 64 + 16 * nt + mr];

#pragma unroll
  for (int mt = 0; mt < 4; ++mt)
#pragma unroll
    for (int r = 0; r < 4; ++r) {
      const int n = 16 * mt + 4 * q + r;
      const size_t base = (size_t)n * (LL * NO * OD) + (size_t)pair * 64;
#pragma unroll
      for (int nt = 0; nt < 4; ++nt)
        V[base + 16 * nt + mr] = acc[mt][nt][r] + bv[nt];
    }
}

// ---------------- k3: fused log_p -> softmax(R over o) -> em accumulate.
// mode 0: uniform R=1/NO (iter 1).  grid 1024 = (n:64, c:16 of 8 l's),
// 4 blocks/CU for latency hiding.  R4-validated math, fp32 V.
__global__ __launch_bounds__(256) void k3_em(
    const float* __restrict__ V, const float* __restrict__ f_a,
    const float* __restrict__ beta_use, const float* __restrict__ mu_s,
    const float* __restrict__ i2v_s, const float* __restrict__ cterm,
    float* __restrict__ S1p, float* __restrict__ S2p,
    float* __restrict__ dnp, float* __restrict__ aUp, const int mode)
{
  const int n = blockIdx.x >> 4;
  const int c = blockIdx.x & 15;
  const int t = threadIdx.x;
  const int o = t >> 3, q = t & 7;
  __shared__ float ttl[8][32];

  float mu8[8], iv8[8];
  float ct = 0.f;
  if (mode) {
    const float4 a0 = *(const float4*)&mu_s[n * 2048 + t * 8];
    const float4 a1 = *(const float4*)&mu_s[n * 2048 + t * 8 + 4];
    mu8[0] = a0.x; mu8[1] = a0.y; mu8[2] = a0.z; mu8[3] = a0.w;
    mu8[4] = a1.x; mu8[5] = a1.y; mu8[6] = a1.z; mu8[7] = a1.w;
    const float4 b0 = *(const float4*)&i2v_s[n * 2048 + t * 8];
    const float4 b1 = *(const float4*)&i2v_s[n * 2048 + t * 8 + 4];
    iv8[0] = b0.x; iv8[1] = b0.y; iv8[2] = b0.z; iv8[3] = b0.w;
    iv8[4] = b1.x; iv8[5] = b1.y; iv8[6] = b1.z; iv8[7] = b1.w;
    ct = cterm[n * NO + o];
  }
  float aS1[8] = {0.f, 0.f, 0.f, 0.f, 0.f, 0.f, 0.f, 0.f};
  float aS2[8] = {0.f, 0.f, 0.f, 0.f, 0.f, 0.f, 0.f, 0.f};
  float dn = 0.f, aU = 0.f;

  for (int g = 0; g < 2; ++g) {
    const int lb = c * 8 + g * 4;
    float Vv[4][8], fa4[4], bu4[4], tt4[4];
#pragma unroll
    for (int u = 0; u < 4; ++u) {
      const int l = lb + u;
      const float4 v0 = *(const float4*)&V[((size_t)n * LL + l) * 2048 + t * 8];
      const float4 v1 = *(const float4*)&V[((size_t)n * LL + l) * 2048 + t * 8 + 4];
      Vv[u][0] = v0.x; Vv[u][1] = v0.y; Vv[u][2] = v0.z; Vv[u][3] = v0.w;
      Vv[u][4] = v1.x; Vv[u][5] = v1.y; Vv[u][6] = v1.z; Vv[u][7] = v1.w;
      fa4[u] = f_a[l * NB + n];
      bu4[u] = beta_use[l];
    }
    if (mode) {
#pragma unroll
      for (int u = 0; u < 4; ++u) {
        float s2 = 0.f;
#pragma unroll
        for (int k = 0; k < 8; ++k) {
          const float d = Vv[u][k] - mu8[k];
          s2 = fmaf(d * d, iv8[k], s2);
        }
        s2 += __shfl_xor(s2, 1);
        s2 += __shfl_xor(s2, 2);
        s2 += __shfl_xor(s2, 4);
        tt4[u] = ct - s2;
      }
      const int sb = (g & 1) * 4;
      if (q == 0) {
#pragma unroll
        for (int u = 0; u < 4; ++u) ttl[sb + u][o] = tt4[u];
      }
      __syncthreads();
#pragma unroll
      for (int u = 0; u < 4; ++u) {
        const float vv = ttl[sb + u][t & 31];
        float m = vv;
#pragma unroll
        for (int msk = 1; msk <= 16; msk <<= 1) m = fmaxf(m, __shfl_xor(m, msk));
        float z = __expf(vv - m);
#pragma unroll
        for (int msk = 1; msk <= 16; msk <<= 1) z += __shfl_xor(z, msk);
        const float wgt = fa4[u] * __expf(tt4[u] - m) / z;
        dn += wgt;
        aU = fmaf(bu4[u], wgt, aU);
#pragma unroll
        for (int k = 0; k < 8; ++k) {
          const float d = Vv[u][k] - mu8[k];
          aS1[k] = fmaf(wgt, Vv[u][k], aS1[k]);
          aS2[k] = fmaf(wgt, d * d, aS2[k]);   // shifted around mu_prev
        }
      }
    } else {
#pragma unroll
      for (int u = 0; u < 4; ++u) {
        const float wgt = fa4[u] * (1.0f / NO);
        dn += wgt;
        aU = fmaf(bu4[u], wgt, aU);
#pragma unroll
        for (int k = 0; k < 8; ++k) {
          aS1[k] = fmaf(wgt, Vv[u][k], aS1[k]);
          aS2[k] = fmaf(wgt * Vv[u][k], Vv[u][k], aS2[k]);
        }
      }
    }
  }
  const int base = ((c * NB + n) * NO + o) * OD + q * 8;
  *(float4*)&S1p[base]     = make_float4(aS1[0], aS1[1], aS1[2], aS1[3]);
  *(float4*)&S1p[base + 4] = make_float4(aS1[4], aS1[5], aS1[6], aS1[7]);
  *(float4*)&S2p[base]     = make_float4(aS2[0], aS2[1], aS2[2], aS2[3]);
  *(float4*)&S2p[base + 4] = make_float4(aS2[4], aS2[5], aS2[6], aS2[7]);
  if (q == 0) {
    dnp[(c * NB + n) * NO + o] = dn;
    aUp[(c * NB + n) * NO + o] = aU;
  }
}

// ---------------- k4: finalize (shifted-variance; first iter uses mup=0)
__global__ __launch_bounds__(256) void k4_fin23(
    const float* __restrict__ S1p, const float* __restrict__ S2p,
    const float* __restrict__ dnp, const float* __restrict__ aUp,
    const float* __restrict__ f_a, const float* __restrict__ beta_ign,
    float* __restrict__ mu_s, float* __restrict__ i2v_s, float* __restrict__ cterm,
    float* __restrict__ out, const int final_iter, const int first)
{
  const int n = blockIdx.x;
  const int t = threadIdx.x;
  const int o = t >> 3, q = t & 7;
  const int j0 = q * 8;
  __shared__ float rA[128];
  if (t < 128) rA[t] = f_a[t * NB + n];
  __syncthreads();
  for (int s = 64; s >= 1; s >>= 1) {
    if (t < s) rA[t] += rA[t + s];
    __syncthreads();
  }
  const float Fsum = rA[0];

  float dn = 0.f, aU = 0.f;
#pragma unroll
  for (int cc = 0; cc < 16; ++cc) {
    dn += dnp[(cc * NB + n) * NO + o];
    aU += aUp[(cc * NB + n) * NO + o];
  }
  const float S0 = dn;
  const float denom = dn + EPSF;
  const float inv_den = 1.0f / denom;

  float S1[8], S2[8];
#pragma unroll
  for (int k = 0; k < 8; ++k) { S1[k] = 0.f; S2[k] = 0.f; }
  for (int cc = 0; cc < 16; ++cc) {
    const int base = ((cc * NB + n) * NO + o) * OD + j0;
    const float4 u0 = *(const float4*)&S1p[base];
    const float4 u1 = *(const float4*)&S1p[base + 4];
    const float4 w0 = *(const float4*)&S2p[base];
    const float4 w1 = *(const float4*)&S2p[base + 4];
    S1[0] += u0.x; S1[1] += u0.y; S1[2] += u0.z; S1[3] += u0.w;
    S1[4] += u1.x; S1[5] += u1.y; S1[6] += u1.z; S1[7] += u1.w;
    S2[0] += w0.x; S2[1] += w0.y; S2[2] += w0.z; S2[3] += w0.w;
    S2[4] += w1.x; S2[5] += w1.y; S2[6] += w1.z; S2[7] += w1.w;
  }
  float mup[8];
  if (first) {
#pragma unroll
    for (int k = 0; k < 8; ++k) mup[k] = 0.f;
  } else {
    const float4 a0 = *(const float4*)&mu_s[n * 2048 + t * 8];
    const float4 a1 = *(const float4*)&mu_s[n * 2048 + t * 8 + 4];
    mup[0] = a0.x; mup[1] = a0.y; mup[2] = a0.z; mup[3] = a0.w;
    mup[4] = a1.x; mup[5] = a1.y; mup[6] = a1.z; mup[7] = a1.w;
  }
  const float aout = aU - beta_ign[o] * (Fsum - dn);

  float mu[8], i2v[8];
  float lacc = 0.f;
#pragma unroll
  for (int k = 0; k < 8; ++k) {
    mu[k] = S1[k] * inv_den;
    const float dd = mu[k] - mup[k];
    float varn = S2[k] - 2.0f * dd * (S1[k] - mup[k] * S0) + dd * dd * S0;
    float var = fmaxf(varn * inv_den, 0.0f);
    i2v[k] = 1.0f / (2.0f * var + EPSF);
    lacc += logf(var + EPSF);
  }
  if (final_iter) {
    if (q == 0) out[n * NO + o] = aout;
    *(float4*)&out[2048 + n * 2048 + t * 8]     = make_float4(mu[0], mu[1], mu[2], mu[3]);
    *(float4*)&out[2048 + n * 2048 + t * 8 + 4] = make_float4(mu[4], mu[5], mu[6], mu[7]);
  } else {
    *(float4*)&mu_s[n * 2048 + t * 8]      = make_float4(mu[0], mu[1], mu[2], mu[3]);
    *(float4*)&mu_s[n * 2048 + t * 8 + 4]  = make_float4(mu[4], mu[5], mu[6], mu[7]);
    *(float4*)&i2v_s[n * 2048 + t * 8]     = make_float4(i2v[0], i2v[1], i2v[2], i2v[3]);
    *(float4*)&i2v_s[n * 2048 + t * 8 + 4] = make_float4(i2v[4], i2v[5], i2v[6], i2v[7]);
    lacc += __shfl_xor(lacc, 1);
    lacc += __shfl_xor(lacc, 2);
    lacc += __shfl_xor(lacc, 4);
    const float lsg = fminf(aout, 0.0f) - log1pf(__expf(-fabsf(aout)));
    if (q == 0) cterm[n * NO + o] = lsg - 0.5f * lacc;
  }
}

extern "C" void kernel_launch(void* const* d_in, const int* in_sizes, int n_in,
                              void* d_out, int out_size, void* d_ws, size_t ws_size,
                              hipStream_t stream) {
  const float* x        = (const float*)d_in[0];
  const float* Wscore   = (const float*)d_in[1];
  const float* Bscore   = (const float*)d_in[2];
  const float* Wcap     = (const float*)d_in[3];
  const float* Bcap     = (const float*)d_in[4];
  const float* Wvote    = (const float*)d_in[5];
  const float* Bvote    = (const float*)d_in[6];
  const float* beta_use = (const float*)d_in[7];
  const float* beta_ign = (const float*)d_in[8];
  // d_in[9] = iters (fixed at 3 by setup; graph capture forbids readback)
  float* out = (float*)d_out;

  float* ws     = (float*)d_ws;
  float* V      = ws;                        // 16777216 fp32
  float* Cpart  = ws;                        // aliases V (pre-k1)
  float* apart  = ws + 3145728;              // aliases V (pre-k1)
  ushort_t* Ah  = (ushort_t*)(ws + 16777216);    // 524288 ushorts
  ushort_t* Al  = Ah + 524288;                   // 524288 ushorts
  float* f_a    = ws + 16777216 + 524288;    // 8192
  float* S1p    = f_a + 8192;                // 2097152
  float* S2p    = S1p + 2097152;             // 2097152
  float* dnp    = S2p + 2097152;             // 32768
  float* aUp    = dnp + 32768;               // 32768
  float* mu_s   = aUp + 32768;               // 131072
  float* i2v_s  = mu_s + 131072;             // 131072
  float* ct     = i2v_s + 131072;            // 2048
  const size_t need = (size_t)(16777216 + 524288 + 8192 + 2 * 2097152 +
                               2 * 32768 + 2 * 131072 + 2048) * sizeof(float);
  if (ws_size < need) return;

  k0a_proj<<<768, 256, 0, stream>>>(x, Wscore, Wcap, Cpart, apart);
  k0b_reduce<<<512, 256, 0, stream>>>(Cpart, Bcap, Ah, Al);
  k0c_fa<<<32, 256, 0, stream>>>(apart, Bscore, f_a);
  k1_votes<<<1024, 256, 0, stream>>>(Ah, Al, Wvote, Bvote, V);
  // iter 1 (uniform R)
  k3_em<<<1024, 256, 0, stream>>>(V, f_a, beta_use, mu_s, i2v_s, ct, S1p, S2p, dnp, aUp, 0);
  k4_fin23<<<64, 256, 0, stream>>>(S1p, S2p, dnp, aUp, f_a, beta_ign, mu_s, i2v_s, ct, out, 0, 1);
  // iter 2
  k3_em<<<1024, 256, 0, stream>>>(V, f_a, beta_use, mu_s, i2v_s, ct, S1p, S2p, dnp, aUp, 1);
  k4_fin23<<<64, 256, 0, stream>>>(S1p, S2p, dnp, aUp, f_a, beta_ign, mu_s, i2v_s, ct, out, 0, 0);
  // iter 3 (final)
  k3_em<<<1024, 256, 0, stream>>>(V, f_a, beta_use, mu_s, i2v_s, ct, S1p, S2p, dnp, aUp, 1);
  k4_fin23<<<64, 256, 0, stream>>>(S1p, S2p, dnp, aUp, f_a, beta_ign, mu_s, i2v_s, ct, out, 1, 0);
}

// Round 8
// 254.925 us; speedup vs baseline: 1.0800x; 1.0800x over previous
//
#include <hip/hip_runtime.h>
#include <math.h>

#define NB 64      // batch N
#define LL 128     // n_in capsules
#define DD 768     // feature dim
#define ID 64      // in_dim
#define OD 64      // out_dim
#define NO 32      // n_out
#define EPSF 1e-8f

typedef unsigned short ushort_t;
typedef __attribute__((ext_vector_type(8))) short bf16x8;
typedef __attribute__((ext_vector_type(4))) float f32x4;

// ws layout (floats):
//  V     : LL*NO*NB*OD = 16777216 fp32  [l][o][n][j]  (wave-contiguous 16KB tiles)
//    Cpart: 6*524288 = 3145728 (aliases V front; consumed pre-k1)
//    apart: 6*8192   = 49152   (aliases V;       consumed pre-k1)
//  Ah/Al : 2 x 524288 ushorts = 524288 floats   dual-bf16 mu_in [l][n][i]
//  f_a   : 8192
//  S1p   : 8*NB*NO*OD = 1048576   chunk partials [c][n][o][j]
//  S2p   : 1048576
//  dnp   : 8*NB*NO = 16384 ; aUp : 16384
//  mu_s  : 131072 ; i2v_s : 131072 ; cterm : 2048

__device__ __forceinline__ float gelu_exact(float v) {
  return 0.5f * v * (1.0f + erff(v * 0.70710678118654752440f));
}
__device__ __forceinline__ float sigmoidf_(float z) {
  return 1.0f / (1.0f + __expf(-z));
}
__device__ __forceinline__ unsigned short f2bf(float f) {  // RNE
  unsigned u = __float_as_uint(f);
  unsigned r = (u + 0x7FFFu + ((u >> 16) & 1u)) >> 16;
  return (unsigned short)r;
}
__device__ __forceinline__ float bf2f(unsigned short s) {
  return __uint_as_float(((unsigned)s) << 16);
}

// ---------------- k0a: split-K partial GEMM for the projections (unchanged).
__global__ __launch_bounds__(256) void k0a_proj(
    const float* __restrict__ x, const float* __restrict__ Wscore,
    const float* __restrict__ Wcap,
    float* __restrict__ Cpart, float* __restrict__ apart)
{
  const int l  = blockIdx.x & 127;
  const int kc = blockIdx.x >> 7;
  const int t = threadIdx.x;
  const int tn = t >> 4;
  const int ti = t & 15;
  __shared__ float Xs[64][68];
  __shared__ float Ws[64][68];
  __shared__ float Ss[64];
  float C[4][4] = {{0.f}};
  float asum[4] = {0.f, 0.f, 0.f, 0.f};

  for (int kt = 0; kt < 2; ++kt) {
    const int kbase = kc * 128 + kt * 64;
#pragma unroll
    for (int r = 0; r < 4; ++r) {
      const int flat = r * 1024 + t * 4;
      const int p = flat >> 6, qq = flat & 63;
      *(float4*)&Xs[p][qq] = *(const float4*)&x[(p * LL + l) * DD + kbase + qq];
      *(float4*)&Ws[p][qq] = *(const float4*)&Wcap[(l * DD + kbase + p) * ID + qq];
    }
    if (t < 16)
      *(float4*)&Ss[4 * t] = *(const float4*)&Wscore[l * DD + kbase + 4 * t];
    __syncthreads();
#pragma unroll 8
    for (int k = 0; k < 64; ++k) {
      float av[4];
      av[0] = Xs[4 * tn + 0][k];
      av[1] = Xs[4 * tn + 1][k];
      av[2] = Xs[4 * tn + 2][k];
      av[3] = Xs[4 * tn + 3][k];
      const float4 b = *(const float4*)&Ws[k][4 * ti];
      const float sk = Ss[k];
#pragma unroll
      for (int a = 0; a < 4; ++a) {
        C[a][0] = fmaf(av[a], b.x, C[a][0]);
        C[a][1] = fmaf(av[a], b.y, C[a][1]);
        C[a][2] = fmaf(av[a], b.z, C[a][2]);
        C[a][3] = fmaf(av[a], b.w, C[a][3]);
        asum[a] = fmaf(av[a], sk, asum[a]);
      }
    }
    __syncthreads();
  }
#pragma unroll
  for (int a = 0; a < 4; ++a)
    *(float4*)&Cpart[kc * 524288 + (l * 64 + 4 * tn + a) * 64 + 4 * ti] =
        make_float4(C[a][0], C[a][1], C[a][2], C[a][3]);
  if (ti == 0) {   // asum complete per K-slice in every ti-thread; no reduce
#pragma unroll
    for (int a = 0; a < 4; ++a)
      apart[kc * 8192 + l * 64 + 4 * tn + a] = asum[a];
  }
}

// ---------------- k0b: reduce partials + bias + gelu -> dual-bf16 mu_in
__global__ __launch_bounds__(256) void k0b_reduce(
    const float* __restrict__ Cpart, const float* __restrict__ Bcap,
    ushort_t* __restrict__ Ah, ushort_t* __restrict__ Al)
{
  const int e = (blockIdx.x * 256 + threadIdx.x) * 4;
  float4 s = *(const float4*)&Cpart[e];
#pragma unroll
  for (int kc = 1; kc < 6; ++kc) {
    const float4 p = *(const float4*)&Cpart[kc * 524288 + e];
    s.x += p.x; s.y += p.y; s.z += p.z; s.w += p.w;
  }
  const int l = e >> 12;
  const int col = e & 63;
  const float4 bc = *(const float4*)&Bcap[l * 64 + col];
  float m[4] = {gelu_exact(s.x + bc.x), gelu_exact(s.y + bc.y),
                gelu_exact(s.z + bc.z), gelu_exact(s.w + bc.w)};
  ushort4 h, lo;
  h.x = f2bf(m[0]); lo.x = f2bf(m[0] - bf2f(h.x));
  h.y = f2bf(m[1]); lo.y = f2bf(m[1] - bf2f(h.y));
  h.z = f2bf(m[2]); lo.z = f2bf(m[2] - bf2f(h.z));
  h.w = f2bf(m[3]); lo.w = f2bf(m[3] - bf2f(h.w));
  *(ushort4*)&Ah[e] = h;
  *(ushort4*)&Al[e] = lo;
}

// ---------------- k0c: reduce asum partials + Bscore -> f_a (sigmoid)
__global__ __launch_bounds__(256) void k0c_fa(
    const float* __restrict__ apart, const float* __restrict__ Bscore,
    float* __restrict__ f_a)
{
  const int e = blockIdx.x * 256 + threadIdx.x;
  float s = 0.f;
#pragma unroll
  for (int kc = 0; kc < 6; ++kc) s += apart[kc * 8192 + e];
  const int l = e >> 6;
  f_a[e] = sigmoidf_(s + Bscore[l]);
}

// ---------------- k1 v4: V = mu_in @ Wvote + Bvote, split-bf16 MFMA (3-term),
// zero LDS, and V stored [l][o][n][j]: each wave writes one CONTIGUOUS 16 KB
// tile (write-locality test). One wave per (l,o). grid 1024 x 256.
__global__ __launch_bounds__(256, 2) void k1_votes(
    const ushort_t* __restrict__ Ah, const ushort_t* __restrict__ Al,
    const float* __restrict__ Wvote, const float* __restrict__ Bvote,
    float* __restrict__ V)
{
  const int t = threadIdx.x;
  const int w = t >> 6;
  const int lane = t & 63;
  const int pair = blockIdx.x * 4 + w;    // l*NO + o
  const int l = pair >> 5;
  const int mr = lane & 15, q = lane >> 4;

  // A fragments (hi/lo) from global (L2-hot: 8 KB per l, shared by 32 o's)
  bf16x8 afh[2][4], afl[2][4];
#pragma unroll
  for (int ks = 0; ks < 2; ++ks)
#pragma unroll
    for (int mt = 0; mt < 4; ++mt) {
      const int off = l * 4096 + (16 * mt + mr) * 64 + ks * 32 + q * 8;
      afh[ks][mt] = *(const bf16x8*)&Ah[off];
      afl[ks][mt] = *(const bf16x8*)&Al[off];
    }

  // B raw fp32 at fragment positions: B[n=16nt+mr][k=ks*32+q*8+d]
  const float* Wt = Wvote + (size_t)pair * 4096;   // [i=k][j=n]
  float braw[2][4][8];
#pragma unroll
  for (int ks = 0; ks < 2; ++ks)
#pragma unroll
    for (int nt = 0; nt < 4; ++nt)
#pragma unroll
      for (int d = 0; d < 8; ++d)
        braw[ks][nt][d] = Wt[(ks * 32 + q * 8 + d) * 64 + 16 * nt + mr];

  f32x4 acc[4][4];
#pragma unroll
  for (int mt = 0; mt < 4; ++mt)
#pragma unroll
    for (int nt = 0; nt < 4; ++nt) {
      f32x4 z = {0.f, 0.f, 0.f, 0.f};
      acc[mt][nt] = z;
    }

#pragma unroll
  for (int ks = 0; ks < 2; ++ks)
#pragma unroll
    for (int nt = 0; nt < 4; ++nt) {
      union { ushort_t u[8]; bf16x8 v; } bh, bl;
#pragma unroll
      for (int d = 0; d < 8; ++d) {
        const float x = braw[ks][nt][d];
        const unsigned short hi = f2bf(x);
        bh.u[d] = hi;
        bl.u[d] = f2bf(x - bf2f(hi));
      }
#pragma unroll
      for (int mt = 0; mt < 4; ++mt) {
        acc[mt][nt] = __builtin_amdgcn_mfma_f32_16x16x32_bf16(
            afh[ks][mt], bh.v, acc[mt][nt], 0, 0, 0);
        acc[mt][nt] = __builtin_amdgcn_mfma_f32_16x16x32_bf16(
            afh[ks][mt], bl.v, acc[mt][nt], 0, 0, 0);
        acc[mt][nt] = __builtin_amdgcn_mfma_f32_16x16x32_bf16(
            afl[ks][mt], bh.v, acc[mt][nt], 0, 0, 0);
      }
    }

  float bv[4];
#pragma unroll
  for (int nt = 0; nt < 4; ++nt) bv[nt] = Bvote[pair * 64 + 16 * nt + mr];

  // store: V[pair][n][j] — contiguous 16 KB per wave
  float* Vt = V + (size_t)pair * 4096;
#pragma unroll
  for (int mt = 0; mt < 4; ++mt)
#pragma unroll
    for (int r = 0; r < 4; ++r) {
      const int n = 16 * mt + 4 * q + r;
#pragma unroll
      for (int nt = 0; nt < 4; ++nt)
        Vt[n * 64 + 16 * nt + mr] = acc[mt][nt][r] + bv[nt];
    }
}

// ---------------- k3 v3: fused log_p -> softmax(R over o) -> em accumulate.
// mode 0: uniform R=1/NO (iter 1).  grid 512 = (n:64, c:8 of 16 l's).
// 8 l's per barrier (2 barriers/block), double-buffered ttl, deep load ILP.
__global__ __launch_bounds__(256) void k3_em(
    const float* __restrict__ V, const float* __restrict__ f_a,
    const float* __restrict__ beta_use, const float* __restrict__ mu_s,
    const float* __restrict__ i2v_s, const float* __restrict__ cterm,
    float* __restrict__ S1p, float* __restrict__ S2p,
    float* __restrict__ dnp, float* __restrict__ aUp, const int mode)
{
  const int n = blockIdx.x >> 3;
  const int c = blockIdx.x & 7;
  const int t = threadIdx.x;
  const int o = t >> 3, q = t & 7;
  __shared__ float ttl[2][8][32];

  float mu8[8], iv8[8];
  float ct = 0.f;
  if (mode) {
    const float4 a0 = *(const float4*)&mu_s[n * 2048 + t * 8];
    const float4 a1 = *(const float4*)&mu_s[n * 2048 + t * 8 + 4];
    mu8[0] = a0.x; mu8[1] = a0.y; mu8[2] = a0.z; mu8[3] = a0.w;
    mu8[4] = a1.x; mu8[5] = a1.y; mu8[6] = a1.z; mu8[7] = a1.w;
    const float4 b0 = *(const float4*)&i2v_s[n * 2048 + t * 8];
    const float4 b1 = *(const float4*)&i2v_s[n * 2048 + t * 8 + 4];
    iv8[0] = b0.x; iv8[1] = b0.y; iv8[2] = b0.z; iv8[3] = b0.w;
    iv8[4] = b1.x; iv8[5] = b1.y; iv8[6] = b1.z; iv8[7] = b1.w;
    ct = cterm[n * NO + o];
  }
  float aS1[8] = {0.f, 0.f, 0.f, 0.f, 0.f, 0.f, 0.f, 0.f};
  float aS2[8] = {0.f, 0.f, 0.f, 0.f, 0.f, 0.f, 0.f, 0.f};
  float dn = 0.f, aU = 0.f;

  for (int g = 0; g < 2; ++g) {
    const int lb = c * 16 + g * 8;
    float Vv[8][8], fa8[8], bu8[8];
#pragma unroll
    for (int u = 0; u < 8; ++u) {
      const int l = lb + u;
      const float* vr = V + ((size_t)(l * NO + o)) * 4096 + n * 64 + q * 8;
      const float4 v0 = *(const float4*)&vr[0];
      const float4 v1 = *(const float4*)&vr[4];
      Vv[u][0] = v0.x; Vv[u][1] = v0.y; Vv[u][2] = v0.z; Vv[u][3] = v0.w;
      Vv[u][4] = v1.x; Vv[u][5] = v1.y; Vv[u][6] = v1.z; Vv[u][7] = v1.w;
      fa8[u] = f_a[l * NB + n];
      bu8[u] = beta_use[l];
    }
    if (mode) {
      float tt8[8];
#pragma unroll
      for (int u = 0; u < 8; ++u) {
        float s2 = 0.f;
#pragma unroll
        for (int k = 0; k < 8; ++k) {
          const float d = Vv[u][k] - mu8[k];
          s2 = fmaf(d * d, iv8[k], s2);
        }
        s2 += __shfl_xor(s2, 1);
        s2 += __shfl_xor(s2, 2);
        s2 += __shfl_xor(s2, 4);
        tt8[u] = ct - s2;
      }
      if (q == 0) {
#pragma unroll
        for (int u = 0; u < 8; ++u) ttl[g][u][o] = tt8[u];
      }
      __syncthreads();
#pragma unroll
      for (int u = 0; u < 8; ++u) {
        const float vv = ttl[g][u][t & 31];
        float m = vv;
#pragma unroll
        for (int msk = 1; msk <= 16; msk <<= 1) m = fmaxf(m, __shfl_xor(m, msk));
        float z = __expf(vv - m);
#pragma unroll
        for (int msk = 1; msk <= 16; msk <<= 1) z += __shfl_xor(z, msk);
        const float wgt = fa8[u] * __expf(tt8[u] - m) / z;
        dn += wgt;
        aU = fmaf(bu8[u], wgt, aU);
#pragma unroll
        for (int k = 0; k < 8; ++k) {
          const float d = Vv[u][k] - mu8[k];
          aS1[k] = fmaf(wgt, Vv[u][k], aS1[k]);
          aS2[k] = fmaf(wgt, d * d, aS2[k]);   // shifted around mu_prev
        }
      }
    } else {
#pragma unroll
      for (int u = 0; u < 8; ++u) {
        const float wgt = fa8[u] * (1.0f / NO);
        dn += wgt;
        aU = fmaf(bu8[u], wgt, aU);
#pragma unroll
        for (int k = 0; k < 8; ++k) {
          aS1[k] = fmaf(wgt, Vv[u][k], aS1[k]);
          aS2[k] = fmaf(wgt * Vv[u][k], Vv[u][k], aS2[k]);
        }
      }
    }
  }
  const int base = ((c * NB + n) * NO + o) * OD + q * 8;
  *(float4*)&S1p[base]     = make_float4(aS1[0], aS1[1], aS1[2], aS1[3]);
  *(float4*)&S1p[base + 4] = make_float4(aS1[4], aS1[5], aS1[6], aS1[7]);
  *(float4*)&S2p[base]     = make_float4(aS2[0], aS2[1], aS2[2], aS2[3]);
  *(float4*)&S2p[base + 4] = make_float4(aS2[4], aS2[5], aS2[6], aS2[7]);
  if (q == 0) {
    dnp[(c * NB + n) * NO + o] = dn;
    aUp[(c * NB + n) * NO + o] = aU;
  }
}

// ---------------- k4: finalize (shifted-variance; first iter uses mup=0)
__global__ __launch_bounds__(256) void k4_fin23(
    const float* __restrict__ S1p, const float* __restrict__ S2p,
    const float* __restrict__ dnp, const float* __restrict__ aUp,
    const float* __restrict__ f_a, const float* __restrict__ beta_ign,
    float* __restrict__ mu_s, float* __restrict__ i2v_s, float* __restrict__ cterm,
    float* __restrict__ out, const int final_iter, const int first)
{
  const int n = blockIdx.x;
  const int t = threadIdx.x;
  const int o = t >> 3, q = t & 7;
  const int j0 = q * 8;
  __shared__ float rA[128];
  if (t < 128) rA[t] = f_a[t * NB + n];
  __syncthreads();
  for (int s = 64; s >= 1; s >>= 1) {
    if (t < s) rA[t] += rA[t + s];
    __syncthreads();
  }
  const float Fsum = rA[0];

  float dn = 0.f, aU = 0.f;
#pragma unroll
  for (int cc = 0; cc < 8; ++cc) {
    dn += dnp[(cc * NB + n) * NO + o];
    aU += aUp[(cc * NB + n) * NO + o];
  }
  const float S0 = dn;
  const float denom = dn + EPSF;
  const float inv_den = 1.0f / denom;

  float S1[8], S2[8];
#pragma unroll
  for (int k = 0; k < 8; ++k) { S1[k] = 0.f; S2[k] = 0.f; }
  for (int cc = 0; cc < 8; ++cc) {
    const int base = ((cc * NB + n) * NO + o) * OD + j0;
    const float4 u0 = *(const float4*)&S1p[base];
    const float4 u1 = *(const float4*)&S1p[base + 4];
    const float4 w0 = *(const float4*)&S2p[base];
    const float4 w1 = *(const float4*)&S2p[base + 4];
    S1[0] += u0.x; S1[1] += u0.y; S1[2] += u0.z; S1[3] += u0.w;
    S1[4] += u1.x; S1[5] += u1.y; S1[6] += u1.z; S1[7] += u1.w;
    S2[0] += w0.x; S2[1] += w0.y; S2[2] += w0.z; S2[3] += w0.w;
    S2[4] += w1.x; S2[5] += w1.y; S2[6] += w1.z; S2[7] += w1.w;
  }
  float mup[8];
  if (first) {
#pragma unroll
    for (int k = 0; k < 8; ++k) mup[k] = 0.f;
  } else {
    const float4 a0 = *(const float4*)&mu_s[n * 2048 + t * 8];
    const float4 a1 = *(const float4*)&mu_s[n * 2048 + t * 8 + 4];
    mup[0] = a0.x; mup[1] = a0.y; mup[2] = a0.z; mup[3] = a0.w;
    mup[4] = a1.x; mup[5] = a1.y; mup[6] = a1.z; mup[7] = a1.w;
  }
  const float aout = aU - beta_ign[o] * (Fsum - dn);

  float mu[8], i2v[8];
  float lacc = 0.f;
#pragma unroll
  for (int k = 0; k < 8; ++k) {
    mu[k] = S1[k] * inv_den;
    const float dd = mu[k] - mup[k];
    float varn = S2[k] - 2.0f * dd * (S1[k] - mup[k] * S0) + dd * dd * S0;
    float var = fmaxf(varn * inv_den, 0.0f);
    i2v[k] = 1.0f / (2.0f * var + EPSF);
    lacc += logf(var + EPSF);
  }
  if (final_iter) {
    if (q == 0) out[n * NO + o] = aout;
    *(float4*)&out[2048 + n * 2048 + t * 8]     = make_float4(mu[0], mu[1], mu[2], mu[3]);
    *(float4*)&out[2048 + n * 2048 + t * 8 + 4] = make_float4(mu[4], mu[5], mu[6], mu[7]);
  } else {
    *(float4*)&mu_s[n * 2048 + t * 8]      = make_float4(mu[0], mu[1], mu[2], mu[3]);
    *(float4*)&mu_s[n * 2048 + t * 8 + 4]  = make_float4(mu[4], mu[5], mu[6], mu[7]);
    *(float4*)&i2v_s[n * 2048 + t * 8]     = make_float4(i2v[0], i2v[1], i2v[2], i2v[3]);
    *(float4*)&i2v_s[n * 2048 + t * 8 + 4] = make_float4(i2v[4], i2v[5], i2v[6], i2v[7]);
    lacc += __shfl_xor(lacc, 1);
    lacc += __shfl_xor(lacc, 2);
    lacc += __shfl_xor(lacc, 4);
    const float lsg = fminf(aout, 0.0f) - log1pf(__expf(-fabsf(aout)));
    if (q == 0) cterm[n * NO + o] = lsg - 0.5f * lacc;
  }
}

extern "C" void kernel_launch(void* const* d_in, const int* in_sizes, int n_in,
                              void* d_out, int out_size, void* d_ws, size_t ws_size,
                              hipStream_t stream) {
  const float* x        = (const float*)d_in[0];
  const float* Wscore   = (const float*)d_in[1];
  const float* Bscore   = (const float*)d_in[2];
  const float* Wcap     = (const float*)d_in[3];
  const float* Bcap     = (const float*)d_in[4];
  const float* Wvote    = (const float*)d_in[5];
  const float* Bvote    = (const float*)d_in[6];
  const float* beta_use = (const float*)d_in[7];
  const float* beta_ign = (const float*)d_in[8];
  // d_in[9] = iters (fixed at 3 by setup; graph capture forbids readback)
  float* out = (float*)d_out;

  float* ws     = (float*)d_ws;
  float* V      = ws;                        // 16777216 fp32, [l][o][n][j]
  float* Cpart  = ws;                        // aliases V (pre-k1)
  float* apart  = ws + 3145728;              // aliases V (pre-k1)
  ushort_t* Ah  = (ushort_t*)(ws + 16777216);    // 524288 ushorts
  ushort_t* Al  = Ah + 524288;                   // 524288 ushorts
  float* f_a    = ws + 16777216 + 524288;    // 8192
  float* S1p    = f_a + 8192;                // 1048576
  float* S2p    = S1p + 1048576;             // 1048576
  float* dnp    = S2p + 1048576;             // 16384
  float* aUp    = dnp + 16384;               // 16384
  float* mu_s   = aUp + 16384;               // 131072
  float* i2v_s  = mu_s + 131072;             // 131072
  float* ct     = i2v_s + 131072;            // 2048
  const size_t need = (size_t)(16777216 + 524288 + 8192 + 2 * 1048576 +
                               2 * 16384 + 2 * 131072 + 2048) * sizeof(float);
  if (ws_size < need) return;

  k0a_proj<<<768, 256, 0, stream>>>(x, Wscore, Wcap, Cpart, apart);
  k0b_reduce<<<512, 256, 0, stream>>>(Cpart, Bcap, Ah, Al);
  k0c_fa<<<32, 256, 0, stream>>>(apart, Bscore, f_a);
  k1_votes<<<1024, 256, 0, stream>>>(Ah, Al, Wvote, Bvote, V);
  // iter 1 (uniform R)
  k3_em<<<512, 256, 0, stream>>>(V, f_a, beta_use, mu_s, i2v_s, ct, S1p, S2p, dnp, aUp, 0);
  k4_fin23<<<64, 256, 0, stream>>>(S1p, S2p, dnp, aUp, f_a, beta_ign, mu_s, i2v_s, ct, out, 0, 1);
  // iter 2
  k3_em<<<512, 256, 0, stream>>>(V, f_a, beta_use, mu_s, i2v_s, ct, S1p, S2p, dnp, aUp, 1);
  k4_fin23<<<64, 256, 0, stream>>>(S1p, S2p, dnp, aUp, f_a, beta_ign, mu_s, i2v_s, ct, out, 0, 0);
  // iter 3 (final)
  k3_em<<<512, 256, 0, stream>>>(V, f_a, beta_use, mu_s, i2v_s, ct, S1p, S2p, dnp, aUp, 1);
  k4_fin23<<<64, 256, 0, stream>>>(S1p, S2p, dnp, aUp, f_a, beta_ign, mu_s, i2v_s, ct, out, 1, 0);
}